// Round 10
// baseline (1153.491 us; speedup 1.0000x reference)
//
#include <hip/hip_runtime.h>
#include <hip/hip_bf16.h>

// Problem constants (KoopmanKernelSeq2Seq)
#define M_  512
#define L_  16
#define O_  32
#define D_  64
#define B_  16
#define ML  8192          // M_*L_
#define SLOT (B_*ML)      // 131072 elements per scan slot

typedef __attribute__((ext_vector_type(8))) short short8;
typedef __attribute__((ext_vector_type(4))) float f32x4;

static constexpr float GAMMA = 1.0f / 128.0f;          // 1/(2*D)
static constexpr float SCALE = 0.0441941738241592f;    // 512^-0.5

__device__ __forceinline__ float sqdiff4(const float4& x, const float4& y) {
    float dx = x.x - y.x, dy = x.y - y.y, dz = x.z - y.z, dw = x.w - y.w;
    return dx*dx + dy*dy + dz*dz + dw*dw;
}

__device__ __forceinline__ unsigned short f2bf(float x) {   // RNE f32->bf16
    unsigned u = __float_as_uint(x);
    u = (u + 0x7FFFu + ((u >> 16) & 1u)) >> 16;
    return (unsigned short)u;
}

// ---- cast+pack koopman f32 -> bf16 MFMA-fragment order, fully nontemporal.
// Gp lives ONLY in HBM (nt stores never allocate in L2/L3); the f32 read is
// nt too (read-once, don't pollute). 32768 blocks -> full-device streaming.
// Gp short-index ((mt*256 + ks)*64 + lane)*8:
//   row = mt*16 + (lane&15), k = ks*32 + (lane>>4)*8 .. +8
__global__ __launch_bounds__(256) void k_cast_pack(const float* __restrict__ G,
                                                   unsigned short* __restrict__ Gp) {
    int wid  = (blockIdx.x << 2) + (threadIdx.x >> 6);   // 131072 waves
    int l    = threadIdx.x & 63;
    int mt = wid >> 8;            // 0..511
    int ks = wid & 255;           // 0..255
    int r  = l & 15;
    int kk = l >> 4;
    const float* src = G + (size_t)(mt * 16 + r) * ML + ks * 32 + kk * 8;
    f32x4 a = __builtin_nontemporal_load((const f32x4*)src);
    f32x4 b = __builtin_nontemporal_load((const f32x4*)(src + 4));
    union { short8 v; unsigned short u[8]; } o;
    o.u[0] = f2bf(a.x); o.u[1] = f2bf(a.y); o.u[2] = f2bf(a.z); o.u[3] = f2bf(a.w);
    o.u[4] = f2bf(b.x); o.u[5] = f2bf(b.y); o.u[6] = f2bf(b.z); o.u[7] = f2bf(b.w);
    __builtin_nontemporal_store(o.v, (short8*)(Gp + ((size_t)(mt * 256 + ks) * 64 + l) * 8));
}

// ---- out0: RBF(nys_X, inps), dual write f32 + bf16 ----
__global__ __launch_bounds__(256) void k_out0_dual(const float* __restrict__ inps,
                                                   const float* __restrict__ X,
                                                   float* __restrict__ S0,
                                                   unsigned short* __restrict__ C0) {
    int idx = blockIdx.x * 256 + threadIdx.x;          // B*M*L = 131072
    int l = idx & (L_ - 1);
    int m = (idx >> 4) & (M_ - 1);
    int b = idx >> 13;
    const float* xr = X + m * D_;
    const float* yr = inps + (b * L_ + l) * D_;
    float d2 = 0.f;
#pragma unroll
    for (int d = 0; d < D_; d += 4) {
        float4 xv = *(const float4*)(xr + d);
        float4 yv = *(const float4*)(yr + d);
        d2 += sqdiff4(xv, yv);
    }
    float v = SCALE * expf(-GAMMA * d2);
    S0[idx] = v;
    C0[idx] = f2bf(v);
}

// f32-only variant (fallback path)
__global__ __launch_bounds__(256) void k_out0(const float* __restrict__ inps,
                                              const float* __restrict__ X,
                                              float* __restrict__ out0) {
    int idx = blockIdx.x * 256 + threadIdx.x;
    int l = idx & (L_ - 1);
    int m = (idx >> 4) & (M_ - 1);
    int b = idx >> 13;
    const float* xr = X + m * D_;
    const float* yr = inps + (b * L_ + l) * D_;
    float d2 = 0.f;
#pragma unroll
    for (int d = 0; d < D_; d += 4) {
        float4 xv = *(const float4*)(xr + d);
        float4 yv = *(const float4*)(yr + d);
        d2 += sqdiff4(xv, yv);
    }
    out0[idx] = SCALE * expf(-GAMMA * d2);
}

// ---- KY = RBF(nys_Y, nys_Y) * scale ----
__global__ __launch_bounds__(256) void k_ky(const float* __restrict__ Y,
                                            float* __restrict__ KY) {
    int idx = blockIdx.x * 256 + threadIdx.x;          // 512*512
    int j = idx & (M_ - 1);
    int i = idx >> 9;
    const float* yi = Y + i * D_;
    const float* yj = Y + j * D_;
    float d2 = 0.f;
#pragma unroll
    for (int d = 0; d < D_; d += 4) {
        float4 a = *(const float4*)(yi + d);
        float4 b = *(const float4*)(yj + d);
        d2 += sqdiff4(a, b);
    }
    KY[idx] = SCALE * expf(-GAMMA * d2);
}

// ---- W[m][a] = sum_j KY[m][j] * Y[j][a] ----
__global__ __launch_bounds__(256) void k_w(const float* __restrict__ KY,
                                           const float* __restrict__ Y,
                                           float* __restrict__ W) {
    int idx = blockIdx.x * 256 + threadIdx.x;          // 512*64
    int a = idx & (D_ - 1);
    int m = idx >> 6;
    float acc = 0.f;
    for (int j = 0; j < M_; ++j)
        acc = fmaf(KY[m * M_ + j], Y[j * D_ + a], acc);
    W[idx] = acc;
}

// ---- scan step: packed-G, ALL G loads nontemporal (pure HBM stream).
// 256 blocks x 512 thr (8 waves). Block owns rows [bx*32,+32) as two 16-row
// tiles; wave w = K-chunk [w*1024,+1024) = 32 MFMA k-slices; both tiles
// share the B fragment (carry stays L2-cached). 8 K-partials LDS-reduced.
__global__ __launch_bounds__(512, 4) void k_step_nt(const unsigned short* __restrict__ Gp,
                                                    const unsigned short* __restrict__ Cin,
                                                    float* __restrict__ Sout,
                                                    unsigned short* __restrict__ Cout) {
    const int bx   = blockIdx.x;
    const int w    = threadIdx.x >> 6;
    const int lane = threadIdx.x & 63;
    const int r    = lane & 15;
    const int kk   = lane >> 4;
    const size_t kbase = (size_t)w * 1024 + kk * 8;
    const int mt0 = bx * 2, mt1 = bx * 2 + 1;

    const unsigned short* ap0 = Gp + ((size_t)(mt0 * 256 + w * 32) * 64 + lane) * 8;
    const unsigned short* ap1 = Gp + ((size_t)(mt1 * 256 + w * 32) * 64 + lane) * 8;
    const unsigned short* bp  = Cin + (size_t)r * ML + kbase;

    f32x4 acc0 = {0.f, 0.f, 0.f, 0.f};
    f32x4 acc1 = {0.f, 0.f, 0.f, 0.f};
#pragma unroll 4
    for (int it = 0; it < 32; ++it) {
        short8 bv = *(const short8*)(bp + it * 32);
        short8 a0 = __builtin_nontemporal_load((const short8*)(ap0 + (size_t)it * 512));
        short8 a1 = __builtin_nontemporal_load((const short8*)(ap1 + (size_t)it * 512));
        acc0 = __builtin_amdgcn_mfma_f32_16x16x32_bf16(a0, bv, acc0, 0, 0, 0);
        acc1 = __builtin_amdgcn_mfma_f32_16x16x32_bf16(a1, bv, acc1, 0, 0, 0);
    }

    // C/D layout: col = lane&15 (batch), row = (lane>>4)*4 + q
    __shared__ float red[2][8][256];
    const int rbase = kk << 2;
#pragma unroll
    for (int q = 0; q < 4; ++q) {
        red[0][w][(rbase + q) * 16 + r] = acc0[q];
        red[1][w][(rbase + q) * 16 + r] = acc1[q];
    }
    __syncthreads();

    const int t = threadIdx.x;          // 512 = 2 tiles * 256
    const int tl = t >> 8;
    const int t2 = t & 255;             // rr*16 + b
    float s = 0.f;
#pragma unroll
    for (int p = 0; p < 8; ++p) s += red[tl][p][t2];
    const int b = t2 & 15;
    const int i = (bx << 5) + (tl << 4) + (t2 >> 4);
    Sout[(size_t)b * ML + i] = s;
    Cout[(size_t)b * ML + i] = f2bf(s);
}

// ---- fallback f32 step (round-1 kernel) ----
__global__ __launch_bounds__(256) void k_step(const float* __restrict__ G,
                                              const float* __restrict__ carry,
                                              float* __restrict__ out) {
    const int i = blockIdx.x;
    const float* __restrict__ grow = G + (size_t)i * ML;
    float acc[B_];
#pragma unroll
    for (int b = 0; b < B_; ++b) acc[b] = 0.f;
    for (int j0 = threadIdx.x * 4; j0 < ML; j0 += 256 * 4) {
        float4 g = *(const float4*)(grow + j0);
#pragma unroll
        for (int b = 0; b < B_; ++b) {
            float4 c = *(const float4*)(carry + b * ML + j0);
            acc[b] = fmaf(g.x, c.x, fmaf(g.y, c.y, fmaf(g.z, c.z, fmaf(g.w, c.w, acc[b]))));
        }
    }
#pragma unroll
    for (int b = 0; b < B_; ++b) {
        float v = acc[b];
#pragma unroll
        for (int off = 32; off > 0; off >>= 1) v += __shfl_down(v, off, 64);
        acc[b] = v;
    }
    __shared__ float red2[4][B_];
    int lane = threadIdx.x & 63;
    int wv   = threadIdx.x >> 6;
    if (lane == 0) {
#pragma unroll
        for (int b = 0; b < B_; ++b) red2[wv][b] = acc[b];
    }
    __syncthreads();
    if (threadIdx.x < B_) {
        float v = red2[0][threadIdx.x] + red2[1][threadIdx.x] +
                  red2[2][threadIdx.x] + red2[3][threadIdx.x];
        out[threadIdx.x * ML + i] = v;
    }
}

// ---- final, W-reuse structure ----
// Block = (b*16 + l), 256 threads: a = t&63, og = t>>6 (wave id).
// Thread accumulates 8 o's (o = og + 4*i). W row loads coalesced, read once
// per block; S loads wave-uniform scalars. f32 math identical to reference.
__global__ __launch_bounds__(256) void k_final2(const float* __restrict__ S,
                                                const float* __restrict__ W,
                                                float* __restrict__ out) {
    const int bid = blockIdx.x;             // 256 = B*L
    const int b = bid >> 4;
    const int l = bid & 15;
    const int a  = threadIdx.x & 63;
    const int og = threadIdx.x >> 6;        // 0..3

    float acc[8];
#pragma unroll
    for (int i = 0; i < 8; ++i) acc[i] = 0.f;

    const float* sbase = S + (size_t)b * ML + l;
    for (int m = 0; m < M_; ++m) {
        float wa = W[m * D_ + a];
#pragma unroll
        for (int i = 0; i < 8; ++i) {
            int o = og + 4 * i;             // 0..31
            float sv = sbase[(size_t)(o + 1) * SLOT + m * L_];
            acc[i] = fmaf(sv, wa, acc[i]);
        }
    }
#pragma unroll
    for (int i = 0; i < 8; ++i) {
        int o = og + 4 * i;
        out[((size_t)bid * O_ + o) * D_ + a] = acc[i];
    }
}

extern "C" void kernel_launch(void* const* d_in, const int* in_sizes, int n_in,
                              void* d_out, int out_size, void* d_ws, size_t ws_size,
                              hipStream_t stream) {
    const float* inps    = (const float*)d_in[0];   // [16,16,64]
    const float* nys_X   = (const float*)d_in[1];   // [512,64]
    const float* nys_Y   = (const float*)d_in[2];   // [512,64]
    const float* koopman = (const float*)d_in[3];   // [8192,8192]
    float* out = (float*)d_out;                     // [16,16,32,64]

    const size_t GB_BYTES  = (size_t)ML * ML * 2;          // 128 MB packed bf16
    const size_t S_BYTES   = (size_t)33 * SLOT * 4;        // 17.3 MB
    const size_t CB_BYTES  = (size_t)33 * SLOT * 2;        // 8.65 MB
    const size_t KY_BYTES  = (size_t)M_ * M_ * 4;
    const size_t W_BYTES   = (size_t)M_ * D_ * 4;
    const size_t NEED_FAST = GB_BYTES + S_BYTES + CB_BYTES + KY_BYTES + W_BYTES;

    if (ws_size >= NEED_FAST) {
        // ---------------- fast bf16-MFMA path ----------------
        unsigned short* Gp = (unsigned short*)d_ws;
        float*          S  = (float*)((char*)d_ws + GB_BYTES);
        unsigned short* Cb = (unsigned short*)((char*)S + S_BYTES);
        float*          KY = (float*)((char*)Cb + CB_BYTES);
        float*          W  = KY + M_ * M_;

        k_cast_pack<<<32768, 256, 0, stream>>>(koopman, Gp);
        k_out0_dual<<<SLOT / 256, 256, 0, stream>>>(inps, nys_X, S, Cb);
        k_ky<<<(M_ * M_) / 256, 256, 0, stream>>>(nys_Y, KY);
        k_w<<<(M_ * D_) / 256, 256, 0, stream>>>(KY, nys_Y, W);

        for (int o = 1; o <= O_; ++o) {
            k_step_nt<<<256, 512, 0, stream>>>(Gp,
                                               Cb + (size_t)(o - 1) * SLOT,
                                               S + (size_t)o * SLOT,
                                               Cb + (size_t)o * SLOT);
        }
        k_final2<<<B_ * L_, 256, 0, stream>>>(S, W, out);
    } else {
        // ---------------- fallback f32 path (round-1) ----------------
        float* S  = (float*)d_ws;
        float* KY = S + (size_t)33 * SLOT;
        float* W  = KY + M_ * M_;

        k_out0<<<SLOT / 256, 256, 0, stream>>>(inps, nys_X, S);
        k_ky<<<(M_ * M_) / 256, 256, 0, stream>>>(nys_Y, KY);
        k_w<<<(M_ * D_) / 256, 256, 0, stream>>>(KY, nys_Y, W);
        for (int o = 1; o <= O_; ++o)
            k_step<<<ML, 256, 0, stream>>>(koopman, S + (size_t)(o - 1) * SLOT,
                                           S + (size_t)o * SLOT);
        k_final2<<<B_ * L_, 256, 0, stream>>>(S, W, out);
    }
}

// Round 11
// 960.905 us; speedup vs baseline: 1.2004x; 1.2004x over previous
//
#include <hip/hip_runtime.h>
#include <hip/hip_bf16.h>

// Problem constants (KoopmanKernelSeq2Seq)
#define M_  512
#define L_  16
#define O_  32
#define D_  64
#define B_  16
#define ML  8192          // M_*L_
#define SLOT (B_*ML)      // 131072 elements per scan slot

typedef __attribute__((ext_vector_type(8))) short short8;
typedef __attribute__((ext_vector_type(4))) float f32x4;

static constexpr float GAMMA = 1.0f / 128.0f;          // 1/(2*D)
static constexpr float SCALE = 0.0441941738241592f;    // 512^-0.5

__device__ __forceinline__ float sqdiff4(const float4& x, const float4& y) {
    float dx = x.x - y.x, dy = x.y - y.y, dz = x.z - y.z, dw = x.w - y.w;
    return dx*dx + dy*dy + dz*dz + dw*dw;
}

__device__ __forceinline__ unsigned short f2bf(float x) {   // RNE f32->bf16
    unsigned u = __float_as_uint(x);
    u = (u + 0x7FFFu + ((u >> 16) & 1u)) >> 16;
    return (unsigned short)u;
}

// ---- cast koopman f32 -> bf16 linear layout (r3's proven ~55us version) ----
__global__ __launch_bounds__(256) void k_cast(const float* __restrict__ G,
                                              unsigned short* __restrict__ Gb) {
    size_t t = (size_t)blockIdx.x * 256 + threadIdx.x;   // 8M threads, 8 elems each
    const f32x4* p = (const f32x4*)(G + t * 8);
    f32x4 a = p[0], b = p[1];
    union { short8 v; unsigned short u[8]; } o;
    o.u[0] = f2bf(a.x); o.u[1] = f2bf(a.y); o.u[2] = f2bf(a.z); o.u[3] = f2bf(a.w);
    o.u[4] = f2bf(b.x); o.u[5] = f2bf(b.y); o.u[6] = f2bf(b.z); o.u[7] = f2bf(b.w);
    *(short8*)(Gb + t * 8) = o.v;
}

// ---- out0: RBF(nys_X, inps), dual write f32 + bf16 ----
__global__ __launch_bounds__(256) void k_out0_dual(const float* __restrict__ inps,
                                                   const float* __restrict__ X,
                                                   float* __restrict__ S0,
                                                   unsigned short* __restrict__ C0) {
    int idx = blockIdx.x * 256 + threadIdx.x;          // B*M*L = 131072
    int l = idx & (L_ - 1);
    int m = (idx >> 4) & (M_ - 1);
    int b = idx >> 13;
    const float* xr = X + m * D_;
    const float* yr = inps + (b * L_ + l) * D_;
    float d2 = 0.f;
#pragma unroll
    for (int d = 0; d < D_; d += 4) {
        float4 xv = *(const float4*)(xr + d);
        float4 yv = *(const float4*)(yr + d);
        d2 += sqdiff4(xv, yv);
    }
    float v = SCALE * expf(-GAMMA * d2);
    S0[idx] = v;
    C0[idx] = f2bf(v);
}

// f32-only variant (fallback path)
__global__ __launch_bounds__(256) void k_out0(const float* __restrict__ inps,
                                              const float* __restrict__ X,
                                              float* __restrict__ out0) {
    int idx = blockIdx.x * 256 + threadIdx.x;
    int l = idx & (L_ - 1);
    int m = (idx >> 4) & (M_ - 1);
    int b = idx >> 13;
    const float* xr = X + m * D_;
    const float* yr = inps + (b * L_ + l) * D_;
    float d2 = 0.f;
#pragma unroll
    for (int d = 0; d < D_; d += 4) {
        float4 xv = *(const float4*)(xr + d);
        float4 yv = *(const float4*)(yr + d);
        d2 += sqdiff4(xv, yv);
    }
    out0[idx] = SCALE * expf(-GAMMA * d2);
}

// ---- KY = RBF(nys_Y, nys_Y) * scale ----
__global__ __launch_bounds__(256) void k_ky(const float* __restrict__ Y,
                                            float* __restrict__ KY) {
    int idx = blockIdx.x * 256 + threadIdx.x;          // 512*512
    int j = idx & (M_ - 1);
    int i = idx >> 9;
    const float* yi = Y + i * D_;
    const float* yj = Y + j * D_;
    float d2 = 0.f;
#pragma unroll
    for (int d = 0; d < D_; d += 4) {
        float4 a = *(const float4*)(yi + d);
        float4 b = *(const float4*)(yj + d);
        d2 += sqdiff4(a, b);
    }
    KY[idx] = SCALE * expf(-GAMMA * d2);
}

// ---- W[m][a] = sum_j KY[m][j] * Y[j][a] ----
__global__ __launch_bounds__(256) void k_w(const float* __restrict__ KY,
                                           const float* __restrict__ Y,
                                           float* __restrict__ W) {
    int idx = blockIdx.x * 256 + threadIdx.x;          // 512*64
    int a = idx & (D_ - 1);
    int m = idx >> 6;
    float acc = 0.f;
    for (int j = 0; j < M_; ++j)
        acc = fmaf(KY[m * M_ + j], Y[j * D_ + a], acc);
    W[idx] = acc;
}

// ---- fused scan step (r3's proven 26.9us/step kernel, unchanged) ----
// Block = 8 waves (512 thr), owns rows [i0, i0+32). Wave w = K-chunk
// [w*1024,(w+1)*1024); 2 m-tiles per wave share one B fragment.
// LDS-reduce 8 partials -> f32 slot + bf16 carry.
__global__ __launch_bounds__(512) void k_step_fused(const unsigned short* __restrict__ Gb,
                                                    const unsigned short* __restrict__ Cin,
                                                    float* __restrict__ Sout,
                                                    unsigned short* __restrict__ Cout) {
    const int i0   = blockIdx.x << 5;            // 256 blocks * 32 rows
    const int w    = threadIdx.x >> 6;           // K-chunk 0..7
    const int lane = threadIdx.x & 63;
    const int r    = lane & 15;
    const int koff = (lane >> 4) << 3;
    const size_t kbase = (size_t)w * 1024 + koff;

    const unsigned short* a0 = Gb + (size_t)(i0 + r)      * ML + kbase;
    const unsigned short* a1 = Gb + (size_t)(i0 + 16 + r) * ML + kbase;
    const unsigned short* bp = Cin + (size_t)r * ML + kbase;

    f32x4 acc0 = {0.f, 0.f, 0.f, 0.f};
    f32x4 acc1 = {0.f, 0.f, 0.f, 0.f};
#pragma unroll 4
    for (int k = 0; k < 1024; k += 32) {
        short8 bv = *(const short8*)(bp + k);
        short8 av0 = *(const short8*)(a0 + k);
        short8 av1 = *(const short8*)(a1 + k);
        acc0 = __builtin_amdgcn_mfma_f32_16x16x32_bf16(av0, bv, acc0, 0, 0, 0);
        acc1 = __builtin_amdgcn_mfma_f32_16x16x32_bf16(av1, bv, acc1, 0, 0, 0);
    }

    // C/D layout: col = lane&15, row = (lane>>4)*4 + q
    __shared__ float red[8][512];
    const int rbase = (lane >> 4) << 2;
#pragma unroll
    for (int q = 0; q < 4; ++q) {
        red[w][(rbase + q) * 16 + r]       = acc0[q];
        red[w][256 + (rbase + q) * 16 + r] = acc1[q];
    }
    __syncthreads();

    // thread tid -> (mt = tid>>8, rr = (tid>>4)&15, b = tid&15)
    const int tid = threadIdx.x;
    float s = red[0][tid] + red[1][tid] + red[2][tid] + red[3][tid] +
              red[4][tid] + red[5][tid] + red[6][tid] + red[7][tid];
    const int b = tid & 15;
    const int i = i0 + (tid >> 4);               // (mt*16 + rr)
    Sout[(size_t)b * ML + i] = s;
    Cout[(size_t)b * ML + i] = f2bf(s);
}

// ---- fallback f32 step (round-1 kernel) ----
__global__ __launch_bounds__(256) void k_step(const float* __restrict__ G,
                                              const float* __restrict__ carry,
                                              float* __restrict__ out) {
    const int i = blockIdx.x;
    const float* __restrict__ grow = G + (size_t)i * ML;
    float acc[B_];
#pragma unroll
    for (int b = 0; b < B_; ++b) acc[b] = 0.f;
    for (int j0 = threadIdx.x * 4; j0 < ML; j0 += 256 * 4) {
        float4 g = *(const float4*)(grow + j0);
#pragma unroll
        for (int b = 0; b < B_; ++b) {
            float4 c = *(const float4*)(carry + b * ML + j0);
            acc[b] = fmaf(g.x, c.x, fmaf(g.y, c.y, fmaf(g.z, c.z, fmaf(g.w, c.w, acc[b]))));
        }
    }
#pragma unroll
    for (int b = 0; b < B_; ++b) {
        float v = acc[b];
#pragma unroll
        for (int off = 32; off > 0; off >>= 1) v += __shfl_down(v, off, 64);
        acc[b] = v;
    }
    __shared__ float red2[4][B_];
    int lane = threadIdx.x & 63;
    int wv   = threadIdx.x >> 6;
    if (lane == 0) {
#pragma unroll
        for (int b = 0; b < B_; ++b) red2[wv][b] = acc[b];
    }
    __syncthreads();
    if (threadIdx.x < B_) {
        float v = red2[0][threadIdx.x] + red2[1][threadIdx.x] +
                  red2[2][threadIdx.x] + red2[3][threadIdx.x];
        out[threadIdx.x * ML + i] = v;
    }
}

// ---- final, W-reuse structure ----
// Block = (b*16 + l), 256 threads: a = t&63, og = t>>6 (wave id).
// Thread accumulates 8 o's (o = og + 4*i). W row loads coalesced, read once
// per block; S loads wave-uniform scalars. f32 math identical to reference.
__global__ __launch_bounds__(256) void k_final2(const float* __restrict__ S,
                                                const float* __restrict__ W,
                                                float* __restrict__ out) {
    const int bid = blockIdx.x;             // 256 = B*L
    const int b = bid >> 4;
    const int l = bid & 15;
    const int a  = threadIdx.x & 63;
    const int og = threadIdx.x >> 6;        // 0..3

    float acc[8];
#pragma unroll
    for (int i = 0; i < 8; ++i) acc[i] = 0.f;

    const float* sbase = S + (size_t)b * ML + l;
    for (int m = 0; m < M_; ++m) {
        float wa = W[m * D_ + a];
#pragma unroll
        for (int i = 0; i < 8; ++i) {
            int o = og + 4 * i;             // 0..31
            float sv = sbase[(size_t)(o + 1) * SLOT + m * L_];
            acc[i] = fmaf(sv, wa, acc[i]);
        }
    }
#pragma unroll
    for (int i = 0; i < 8; ++i) {
        int o = og + 4 * i;
        out[((size_t)bid * O_ + o) * D_ + a] = acc[i];
    }
}

extern "C" void kernel_launch(void* const* d_in, const int* in_sizes, int n_in,
                              void* d_out, int out_size, void* d_ws, size_t ws_size,
                              hipStream_t stream) {
    const float* inps    = (const float*)d_in[0];   // [16,16,64]
    const float* nys_X   = (const float*)d_in[1];   // [512,64]
    const float* nys_Y   = (const float*)d_in[2];   // [512,64]
    const float* koopman = (const float*)d_in[3];   // [8192,8192]
    float* out = (float*)d_out;                     // [16,16,32,64]

    const size_t GB_BYTES  = (size_t)ML * ML * 2;          // 128 MB bf16
    const size_t S_BYTES   = (size_t)33 * SLOT * 4;        // 17.3 MB
    const size_t CB_BYTES  = (size_t)33 * SLOT * 2;        // 8.65 MB
    const size_t KY_BYTES  = (size_t)M_ * M_ * 4;
    const size_t W_BYTES   = (size_t)M_ * D_ * 4;
    const size_t NEED_FAST = GB_BYTES + S_BYTES + CB_BYTES + KY_BYTES + W_BYTES;

    if (ws_size >= NEED_FAST) {
        // ---------------- fast bf16-MFMA path (r3 structure + final2) ----------------
        unsigned short* Gb = (unsigned short*)d_ws;
        float*          S  = (float*)((char*)d_ws + GB_BYTES);
        unsigned short* Cb = (unsigned short*)((char*)S + S_BYTES);
        float*          KY = (float*)((char*)Cb + CB_BYTES);
        float*          W  = KY + M_ * M_;

        k_cast<<<(int)((size_t)ML * ML / 8 / 256), 256, 0, stream>>>(koopman, Gb);
        k_out0_dual<<<SLOT / 256, 256, 0, stream>>>(inps, nys_X, S, Cb);
        k_ky<<<(M_ * M_) / 256, 256, 0, stream>>>(nys_Y, KY);
        k_w<<<(M_ * D_) / 256, 256, 0, stream>>>(KY, nys_Y, W);

        for (int o = 1; o <= O_; ++o) {
            k_step_fused<<<256, 512, 0, stream>>>(Gb,
                                                  Cb + (size_t)(o - 1) * SLOT,
                                                  S + (size_t)o * SLOT,
                                                  Cb + (size_t)o * SLOT);
        }
        k_final2<<<B_ * L_, 256, 0, stream>>>(S, W, out);
    } else {
        // ---------------- fallback f32 path (round-1) ----------------
        float* S  = (float*)d_ws;
        float* KY = S + (size_t)33 * SLOT;
        float* W  = KY + M_ * M_;

        k_out0<<<SLOT / 256, 256, 0, stream>>>(inps, nys_X, S);
        k_ky<<<(M_ * M_) / 256, 256, 0, stream>>>(nys_Y, KY);
        k_w<<<(M_ * D_) / 256, 256, 0, stream>>>(KY, nys_Y, W);
        for (int o = 1; o <= O_; ++o)
            k_step<<<ML, 256, 0, stream>>>(koopman, S + (size_t)(o - 1) * SLOT,
                                           S + (size_t)o * SLOT);
        k_final2<<<B_ * L_, 256, 0, stream>>>(S, W, out);
    }
}